// Round 4
// baseline (98.788 us; speedup 1.0000x reference)
//
#include <hip/hip_runtime.h>
#include <math.h>

#define B 1024
#define O 256
#define D 1024
#define ALPHA 0.005f

// Kernel 0: transpose c[O][D] -> ct[D/4][O] (float4 elements)
// block = one d4-row group, tid = o  -> writes coalesced.
__global__ __launch_bounds__(256) void transpose_c(const float* __restrict__ c,
                                                   float4* __restrict__ ct)
{
    const int o  = threadIdx.x;         // 0..255
    const int d4 = blockIdx.x;          // 0..D/4-1
    const float* src = c + (size_t)o * D + d4 * 4;
    ct[(size_t)d4 * O + o] = make_float4(src[0], src[1], src[2], src[3]);
}

// Kernel 1 (fused): full D reduction + sqrt/temperature + alpha row-correction
// in ONE kernel. 256 blocks x 1024 threads = 16 waves/CU (4/SIMD).
//   o = tid & 255  -> lane dim, c reads coalesced via ct (1 KB/wave/step)
//   r = tid >> 8   -> b-row within block, wave-uniform (readfirstlane'd so the
//                     x address is provably uniform -> scalar-load candidate)
// No partials, no workspace traffic, no third launch.
__global__ __launch_bounds__(1024) void dist_fused(const float* __restrict__ x,
                                                   const float4* __restrict__ ct,
                                                   float* __restrict__ out)
{
    const int tid = threadIdx.x;
    const int o   = tid & 255;
    const int r   = __builtin_amdgcn_readfirstlane(tid >> 8);  // 0..3, wave-uniform
    const int b   = blockIdx.x * 4 + r;

    const float4* cq = ct + o;                           // step O per d4
    const float4* xq = (const float4*)(x + (size_t)b * D);

    float s1 = 0.f, s2 = 0.f;

    #pragma unroll 8
    for (int q = 0; q < D / 4; ++q) {
        const float4 cv = cq[(size_t)q * O];
        const float4 xv = xq[q];
        const float d0 = xv.x - cv.x, d1 = xv.y - cv.y,
                    d2 = xv.z - cv.z, d3 = xv.w - cv.w;
        s1 += __builtin_fabsf(d0); s2 = __builtin_fmaf(d0, d0, s2);
        s1 += __builtin_fabsf(d1); s2 = __builtin_fmaf(d1, d1, s2);
        s1 += __builtin_fabsf(d2); s2 = __builtin_fmaf(d2, d2, s2);
        s1 += __builtin_fabsf(d3); s2 = __builtin_fmaf(d3, d3, s2);
    }

    // v = L1/t1 + L2/t2
    const float v = s1 + 0.5f * __builtin_sqrtf(s2);

    // row-sum over all 256 o's of this b-row (4 waves per row layer)
    float t = v;
    #pragma unroll
    for (int off = 32; off >= 1; off >>= 1)
        t += __shfl_down(t, off, 64);

    __shared__ float ws[16];
    const int w = tid >> 6;                 // wave id 0..15; row layer = w>>2
    if ((tid & 63) == 0) ws[w] = t;
    __syncthreads();
    const float S = ws[r * 4 + 0] + ws[r * 4 + 1] + ws[r * 4 + 2] + ws[r * 4 + 3];

    out[(size_t)b * O + o] = ALPHA * S - (1.0f + ALPHA) * v;
}

extern "C" void kernel_launch(void* const* d_in, const int* in_sizes, int n_in,
                              void* d_out, int out_size, void* d_ws, size_t ws_size,
                              hipStream_t stream) {
    const float* x = (const float*)d_in[0];   // [B, D]
    const float* c = (const float*)d_in[1];   // [O, D]
    float* out = (float*)d_out;               // [B, O]

    float4* ct = (float4*)d_ws;               // [D/4, O] = 1 MB

    transpose_c<<<D / 4, O, 0, stream>>>(c, ct);
    dist_fused<<<B / 4, 1024, 0, stream>>>(x, ct, out);
}